// Round 9
// baseline (205.343 us; speedup 1.0000x reference)
//
#include <hip/hip_runtime.h>
#include <hip/hip_bf16.h>

// SAGAN self-attention v13. B=8, C=64, N=4096, CQ=8.
// Algebraic refactor: out = Wv.(X.P^T)/d + bv  -- V never materialized.
//
// v12 verdict: residual dur_us - attn ~60us is fixed harness cost
// (268MB workspace re-poison visible in trace); attn (52us) is the only
// controllable lever. Step-wall arithmetic: ~2000 cyc/step vs ~400 cyc
// of per-wave work -> the 32 per-step barriers (8-wave lockstep skew +
// LDS serialization around them) dominate.
//
// v13 = v10 loop with 2 SUBSTEPS PER BARRIER (16 barriers, was 32):
//   - registers UNTOUCHED (v11 lesson: +24 regs spilled): kf[2]/xf[2][2]
//     re-indexed per-substep, prefetch distance 1 substep. K-prefetch
//     hides under exp2+barrier+p2; X-prefetch issues right after its
//     consumer MFMA, hides under next p1/exp2.
//   - P: pair base p*16384, dbuf cur*8192, substep u*4096; each 4KB
//     sub-buffer is v10's proven conflict-optimal layout byte-for-byte.
//   - dbuf safety: iteration i+1 writes buffer (i+1)&1 whose readers
//     (iteration i-1's p2) finished before iteration i's barrier.
// Lessons kept: launch_bounds(512,4) + arch<=64 (AGPR rounds 32->64),
//   no setprio/ones-MFMA/XCD-swizzle (v7), masked kf loads (v4),
//   prep v12 (float4 staging, packed uint2 stores).

#define B_   8
#define C_   64
#define N_   4096
#define LOG2E 1.44269504088896340736f

typedef short bf16x8 __attribute__((ext_vector_type(8)));
typedef float f32x4  __attribute__((ext_vector_type(4)));
typedef unsigned int uint32;

#if __has_builtin(__builtin_amdgcn_exp2f)
#define EXP2(x) __builtin_amdgcn_exp2f(x)
#else
#define EXP2(x) __expf((x) * 0.69314718055994530942f)
#endif

__device__ __forceinline__ unsigned short f2bf_rn(float f) {
    union { __hip_bfloat16 h; unsigned short u; } cv;
    cv.h = __float2bfloat16(f);
    return cv.u;
}
__device__ __forceinline__ uint32 pk_rn(float lo, float hi) {
    return (uint32)f2bf_rn(lo) | ((uint32)f2bf_rn(hi) << 16);
}
// RTZ pack (1 v_perm): bias cancels in softmax ratio. Verified R2/R3.
__device__ __forceinline__ uint32 pack_rtz(float lo, float hi) {
    return __builtin_amdgcn_perm(__float_as_uint(hi), __float_as_uint(lo), 0x07060302);
}

// ---------------------------------------------------------------------------
// prep v12 (kept): Xb = bf16(x), Qh/Kh = projections (Q pre-scaled).
// Grid: B * N/64 = 512 blocks, 256 threads.
// ---------------------------------------------------------------------------
__global__ __launch_bounds__(256) void prep_kernel(
    const float* __restrict__ x,
    const float* __restrict__ wq, const float* __restrict__ bq,
    const float* __restrict__ wk, const float* __restrict__ bk,
    unsigned short* __restrict__ Qh, unsigned short* __restrict__ Kh,
    unsigned short* __restrict__ Xb)
{
    __shared__ float Xs[C_][64];
    __shared__ float Wqk[16][C_];
    __shared__ float Bqk[16];

    const int t  = threadIdx.x;
    const int b  = blockIdx.x >> 6;
    const int p0 = (blockIdx.x & 63) << 6;

    #pragma unroll
    for (int k = 0; k < 4; ++k) {
        int i = t + k * 256;
        int o = i >> 6;
        Wqk[o][i & 63] = (o < 8) ? wq[i] * LOG2E : wk[i - 512];
    }
    if (t < 16) Bqk[t] = (t < 8) ? bq[t] * LOG2E : bk[t - 8];

    #pragma unroll
    for (int k = 0; k < 4; ++k) {
        int i = t + k * 256;                 // 1024 float4 total
        int c = i >> 4, p4 = (i & 15) << 2;
        const float4 v = *(const float4*)(x + ((size_t)b * C_ + c) * N_ + p0 + p4);
        *(float4*)&Xs[c][p4] = v;
        uint2 u;
        u.x = pk_rn(v.x, v.y);
        u.y = pk_rn(v.z, v.w);
        *(uint2*)(Xb + ((size_t)b * C_ + c) * N_ + p0 + p4) = u;
    }
    __syncthreads();

    const int pix = t & 63, grp = t >> 6;    // grp wave-uniform
    float a[4];
    #pragma unroll
    for (int r = 0; r < 4; ++r) a[r] = Bqk[grp * 4 + r];
    #pragma unroll
    for (int c = 0; c < C_; ++c) {
        float xv = Xs[c][pix];               // lanes consecutive: conflict-free
        #pragma unroll
        for (int r = 0; r < 4; ++r) a[r] += Wqk[grp * 4 + r][c] * xv;  // broadcast
    }
    uint2 u;
    u.x = pk_rn(a[0], a[1]);
    u.y = pk_rn(a[2], a[3]);
    unsigned short* dst = (grp & 2) ? Kh : Qh;
    *(uint2*)(dst + ((size_t)b * N_ + p0 + pix) * 8 + (grp & 1) * 4) = u;
}

// ---------------------------------------------------------------------------
// attn v13: grid B * N/64 = 512 blocks, 512 threads (8 waves = 4 pairs).
// Pair p: j in [p*1024,+1024), 16 iterations x 64 j (2 substeps x 32 j).
// Wave h of pair: jt=h rows of each substep in p1, channel half h in p2.
// ONE barrier per iteration (16 total, was 32).
// ---------------------------------------------------------------------------
__global__ __launch_bounds__(512, 4) void attn_mfma11_kernel(
    const unsigned short* __restrict__ Qh,
    const unsigned short* __restrict__ Kh,
    const unsigned short* __restrict__ Xb,
    const float* __restrict__ wv, const float* __restrict__ bv,
    float* __restrict__ out)
{
    // LDS map (67584 B; 2 blocks/CU):
    //  loop:   [0,64K)   P: pair p at p*16384, dbuf +cur*8192, substep
    //                    +u*4096; each 4KB sub = v10 layout (qt*1024 +
    //                    l16*64 + XOR-swz offs, conflict-optimal)
    //  epilog: [0,48K)   6 dump slots x 8KB; then [0,16K) Wvs after reads
    //          [48K,64K) Or fp32 [64][64]
    //          [64K,+2K) Dn [8][64] fp32
    __shared__ __align__(16) char smem[67584];

    const int t    = threadIdx.x;
    const int w    = t >> 6;
    const int lane = t & 63;
    const int l16  = lane & 15;
    const int qd   = lane >> 4;
    const int p    = w & 3;     // pair -> j-slice
    const int h    = w >> 2;    // 0: jt0 + c[0,32) ; 1: jt1 + c[32,64)
    const int b    = blockIdx.x >> 6;
    const int i0   = (blockIdx.x & 63) << 6;

    const bf16x8 z8 = {};
    const f32x4  zf = {};

    // Q frags (phase-1 B-operand, B[k=ch][n=q], quads 1-3 zero: K-pad)
    bf16x8 qf[4];
    #pragma unroll
    for (int qt = 0; qt < 4; ++qt) {
        qf[qt] = z8;
        if (qd == 0)
            qf[qt] = *(const bf16x8*)(Qh + ((size_t)b * N_ + i0 + qt * 16 + l16) * 8);
    }

    // K rows for this wave's jt-half; X rows for its channel half.
    const unsigned short* Kp = Kh + ((size_t)b * N_ + p * 1024 + h * 16) * 8;
    const unsigned short* Xp = Xb + ((size_t)b * C_ + h * 32) * N_ + p * 1024;

    f32x4 acc[2][4];   // [ct][qt]: O'(c=h*32+ct*16+qd*4+r, q=qt*16+l16)
    #pragma unroll
    for (int ct = 0; ct < 2; ++ct)
        #pragma unroll
        for (int qt = 0; qt < 4; ++qt) acc[ct][qt] = zf;
    float dsum[4] = {0.f, 0.f, 0.f, 0.f};

    // P addressing (v10-proven XOR swizzle per 4KB sub-buffer)
    const int swz   = (l16 & 3) << 2;
    const int pbase = p * 16384 + l16 * 64;     // + cur*8192 + u*4096
    const int woff  = ((h * 8 + qd * 2) ^ swz) << 2;
    const int roff  = ((qd * 4) ^ swz) << 2;

    // preload iteration 0: kf[u], xf[u][ct] for substeps u=0,1
    bf16x8 kf[2], xf[2][2];
    kf[0] = z8; kf[1] = z8;
    if (qd == 0) {
        kf[0] = *(const bf16x8*)(Kp + (size_t)l16 * 8);
        kf[1] = *(const bf16x8*)(Kp + (size_t)(32 + l16) * 8);
    }
    #pragma unroll
    for (int u = 0; u < 2; ++u)
        #pragma unroll
        for (int ct = 0; ct < 2; ++ct)
            xf[u][ct] = *(const bf16x8*)(Xp + (size_t)(ct * 16 + l16) * N_ + u * 32 + qd * 8);

    #pragma unroll 2
    for (int it = 0; it < 16; ++it) {
        const int cur = it & 1;
        const int jb = it * 64;
        char* pb_ = smem + pbase + cur * 8192;

        // ---- substep 0: p1 + exp/pack ----
        {
            f32x4 sf[4];
            #pragma unroll
            for (int qt = 0; qt < 4; ++qt)
                sf[qt] = __builtin_amdgcn_mfma_f32_16x16x32_bf16(kf[0], qf[qt], zf, 0, 0, 0);
            #pragma unroll
            for (int qt = 0; qt < 4; ++qt) {
                float e0 = EXP2(sf[qt][0]);
                float e1 = EXP2(sf[qt][1]);
                float e2 = EXP2(sf[qt][2]);
                float e3 = EXP2(sf[qt][3]);
                dsum[qt] += (e0 + e1) + (e2 + e3);
                uint2 u;
                u.x = pack_rtz(e0, e1);
                u.y = pack_rtz(e2, e3);
                *(uint2*)(pb_ + qt * 1024 + woff) = u;
            }
        }
        // ---- substep 1: p1 + K-prefetch + exp/pack ----
        {
            f32x4 sf[4];
            #pragma unroll
            for (int qt = 0; qt < 4; ++qt)
                sf[qt] = __builtin_amdgcn_mfma_f32_16x16x32_bf16(kf[1], qf[qt], zf, 0, 0, 0);

            // prefetch next iteration's K pair (kf[0],kf[1] both consumed);
            // latency hides under exp2 + barrier + p2.
            if (it < 15) {
                bf16x8 nk0 = z8, nk1 = z8;
                if (qd == 0) {
                    nk0 = *(const bf16x8*)(Kp + (size_t)(jb + 64 + l16) * 8);
                    nk1 = *(const bf16x8*)(Kp + (size_t)(jb + 96 + l16) * 8);
                }
                kf[0] = nk0;
                kf[1] = nk1;
            }

            #pragma unroll
            for (int qt = 0; qt < 4; ++qt) {
                float e0 = EXP2(sf[qt][0]);
                float e1 = EXP2(sf[qt][1]);
                float e2 = EXP2(sf[qt][2]);
                float e3 = EXP2(sf[qt][3]);
                dsum[qt] += (e0 + e1) + (e2 + e3);
                uint2 u;
                u.x = pack_rtz(e0, e1);
                u.y = pack_rtz(e2, e3);
                *(uint2*)(pb_ + 4096 + qt * 1024 + woff) = u;
            }
        }

        // ONE barrier: both sub-buffers of P[cur] complete (both waves).
        // Writes to P[cur^1] next iteration are safe: its readers
        // (iteration it-1's p2) finished before THIS barrier.
        __syncthreads();

        // ---- p2 substep 0 + X-prefetch for slot 0 ----
        #pragma unroll
        for (int qt = 0; qt < 4; ++qt) {
            bf16x8 pbf = *(const bf16x8*)(pb_ + qt * 1024 + roff);
            #pragma unroll
            for (int ct = 0; ct < 2; ++ct)
                acc[ct][qt] = __builtin_amdgcn_mfma_f32_16x16x32_bf16(xf[0][ct], pbf, acc[ct][qt], 0, 0, 0);
        }
        if (it < 15) {
            #pragma unroll
            for (int ct = 0; ct < 2; ++ct)
                xf[0][ct] = *(const bf16x8*)(Xp + (size_t)(ct * 16 + l16) * N_ + jb + 64 + qd * 8);
        }
        // ---- p2 substep 1 + X-prefetch for slot 1 ----
        #pragma unroll
        for (int qt = 0; qt < 4; ++qt) {
            bf16x8 pbf = *(const bf16x8*)(pb_ + 4096 + qt * 1024 + roff);
            #pragma unroll
            for (int ct = 0; ct < 2; ++ct)
                acc[ct][qt] = __builtin_amdgcn_mfma_f32_16x16x32_bf16(xf[1][ct], pbf, acc[ct][qt], 0, 0, 0);
        }
        if (it < 15) {
            #pragma unroll
            for (int ct = 0; ct < 2; ++ct)
                xf[1][ct] = *(const bf16x8*)(Xp + (size_t)(ct * 16 + l16) * N_ + jb + 96 + qd * 8);
        }
    }

    // ---- denominator partials -> Dn[w][64] at [64K,+2K) ----
    #pragma unroll
    for (int qt = 0; qt < 4; ++qt) {
        float v = dsum[qt];
        v += __shfl_xor(v, 16, 64);
        v += __shfl_xor(v, 32, 64);
        if (qd == 0) *(float*)(smem + 65536 + (w * 64 + qt * 16 + l16) * 4) = v;
    }

    // ---- cross-wave O' reduce: halves reduce independently (v10) ----
    __syncthreads();                                   // S1: loop LDS done
    if (p != 0) {                                      // 6 dumpers, 8KB each
        const int slot = h * 3 + (p - 1);
        char* rb = smem + slot * 8192;
        #pragma unroll
        for (int ct = 0; ct < 2; ++ct)
            #pragma unroll
            for (int qt = 0; qt < 4; ++qt)
                *(f32x4*)(rb + (ct * 4 + qt) * 1024 + lane * 16) = acc[ct][qt];
    }
    __syncthreads();                                   // S2
    if (p == 0) {                                      // w0 (ct01), w4 (ct23)
        #pragma unroll
        for (int rr = 0; rr < 3; ++rr) {
            const char* rb = smem + (h * 3 + rr) * 8192;
            #pragma unroll
            for (int ct = 0; ct < 2; ++ct)
                #pragma unroll
                for (int qt = 0; qt < 4; ++qt)
                    acc[ct][qt] += *(const f32x4*)(rb + (ct * 4 + qt) * 1024 + lane * 16);
        }
        float* Or = (float*)(smem + 49152);
        #pragma unroll
        for (int ct = 0; ct < 2; ++ct)
            #pragma unroll
            for (int qt = 0; qt < 4; ++qt)
                #pragma unroll
                for (int r = 0; r < 4; ++r)
                    Or[(h * 32 + ct * 16 + qd * 4 + r) * 64 + qt * 16 + l16] = acc[ct][qt][r];
    }
    __syncthreads();                                   // S3: dump reads done
    {   // stage Wv fp32 -> [0,16K)
        float* Wvs = (float*)smem;
        for (int i = t; i < 4096; i += 512) Wvs[i] = wv[i];
    }
    __syncthreads();                                   // S4

    // ---- epilogue: out = Wv.O'/d + bv, fp32, all 8 waves ----
    const int q = t & 63, grp = t >> 6;                // grp = wave = c-group
    const float* Wvs = (const float*)smem;
    const float* Or  = (const float*)(smem + 49152);
    const float* Dn  = (const float*)(smem + 65536);
    float dtot = 0.f;
    #pragma unroll
    for (int r = 0; r < 8; ++r) dtot += Dn[r * 64 + q];
    const float inv = 1.0f / dtot;
    float o[8];
    #pragma unroll
    for (int r = 0; r < 8; ++r) o[r] = 0.f;
    for (int k = 0; k < 64; ++k) {
        float ov = Or[k * 64 + q];                      // lanes consecutive q
        #pragma unroll
        for (int r = 0; r < 8; ++r)
            o[r] += Wvs[(grp * 8 + r) * 64 + k] * ov;   // broadcast
    }
    #pragma unroll
    for (int r = 0; r < 8; ++r)
        out[((size_t)b * C_ + grp * 8 + r) * N_ + i0 + q] = o[r] * inv + bv[grp * 8 + r];
}

// ---------------------------------------------------------------------------
// Fallback (workspace too small): round-1 fused fp32 flash kernel (verified).
// ---------------------------------------------------------------------------
__global__ __launch_bounds__(256) void attn_fused_fallback(
    const float* __restrict__ x,
    const float* __restrict__ wq, const float* __restrict__ bq,
    const float* __restrict__ wk, const float* __restrict__ bk,
    const float* __restrict__ wv, const float* __restrict__ bv,
    float* __restrict__ out)
{
    __shared__ float Qs[64][8];
    __shared__ float Ks[8][64];
    __shared__ float Vs[64][C_];
    __shared__ float Ws[64][64 + 1];
    __shared__ float Xs[C_ * 64];
    __shared__ float Wks[8][C_];
    __shared__ float Wvs[C_][C_ + 1];

    const int t     = threadIdx.x;
    const int b     = blockIdx.x / (N_ / 64);
    const int i0    = (blockIdx.x % (N_ / 64)) * 64;
    const int jlane = t & 63;
    const int wgrp  = t >> 6;

    for (int l = t; l < 8 * C_;  l += 256) Wks[l >> 6][l & 63] = wk[l];
    for (int l = t; l < C_ * C_; l += 256) Wvs[l >> 6][l & 63] = wv[l];
    for (int l = t; l < C_ * 64; l += 256)
        Xs[(l >> 6) * 64 + (l & 63)] = x[((size_t)b * C_ + (l >> 6)) * N_ + i0 + (l & 63)];
    __syncthreads();
    {
        int qi = jlane;
        #pragma unroll
        for (int r = 0; r < 2; ++r) {
            int cc = wgrp * 2 + r;
            float a = bq[cc];
            for (int c = 0; c < C_; ++c) a += wq[cc * C_ + c] * Xs[c * 64 + qi];
            Qs[qi][cc] = a;
        }
    }
    __syncthreads();

    const int qi2 = t >> 2;
    const int cb  = (t & 3) << 4;
    float accv[16];
    #pragma unroll
    for (int r = 0; r < 16; ++r) accv[r] = 0.f;
    float denom = 0.f;

    for (int j0 = 0; j0 < N_; j0 += 64) {
        for (int l = t; l < C_ * 64; l += 256)
            Xs[(l >> 6) * 64 + (l & 63)] = x[((size_t)b * C_ + (l >> 6)) * N_ + j0 + (l & 63)];
        __syncthreads();
        {
            int j = jlane;
            #pragma unroll
            for (int r = 0; r < 2; ++r) {
                int cc = wgrp * 2 + r;
                float a = bk[cc];
                for (int c = 0; c < C_; ++c) a += Wks[cc][c] * Xs[c * 64 + j];
                Ks[cc][j] = a;
            }
        }
        {
            int vc = jlane;
            #pragma unroll 2
            for (int r = 0; r < 16; ++r) {
                int j = wgrp * 16 + r;
                float a = bv[vc];
                for (int c = 0; c < C_; ++c) a += Wvs[vc][c] * Xs[c * 64 + j];
                Vs[j][vc] = a;
            }
        }
        __syncthreads();
        {
            float kreg[8];
            #pragma unroll
            for (int cc = 0; cc < 8; ++cc) kreg[cc] = Ks[cc][jlane];
            #pragma unroll 4
            for (int r = 0; r < 16; ++r) {
                int qi = wgrp * 16 + r;
                float e = 0.f;
                #pragma unroll
                for (int cc = 0; cc < 8; ++cc) e += Qs[qi][cc] * kreg[cc];
                Ws[qi][jlane] = __expf(e);
            }
        }
        __syncthreads();
        #pragma unroll 4
        for (int j = 0; j < 64; ++j) {
            float wv2 = Ws[qi2][j];
            denom += wv2;
            const float4* vrow = (const float4*)(&Vs[j][cb]);
            float4 v0 = vrow[0], v1 = vrow[1], v2 = vrow[2], v3 = vrow[3];
            accv[0]  += wv2 * v0.x; accv[1]  += wv2 * v0.y; accv[2]  += wv2 * v0.z; accv[3]  += wv2 * v0.w;
            accv[4]  += wv2 * v1.x; accv[5]  += wv2 * v1.y; accv[6]  += wv2 * v1.z; accv[7]  += wv2 * v1.w;
            accv[8]  += wv2 * v2.x; accv[9]  += wv2 * v2.y; accv[10] += wv2 * v2.z; accv[11] += wv2 * v2.w;
            accv[12] += wv2 * v3.x; accv[13] += wv2 * v3.y; accv[14] += wv2 * v3.z; accv[15] += wv2 * v3.w;
        }
        __syncthreads();
    }

    const float inv = 1.0f / denom;
    #pragma unroll
    for (int r = 0; r < 16; ++r)
        out[((size_t)b * C_ + cb + r) * N_ + i0 + qi2] = accv[r] * inv;
}

// ---------------------------------------------------------------------------
extern "C" void kernel_launch(void* const* d_in, const int* in_sizes, int n_in,
                              void* d_out, int out_size, void* d_ws, size_t ws_size,
                              hipStream_t stream)
{
    const float* x  = (const float*)d_in[0];
    const float* wq = (const float*)d_in[1];
    const float* bq = (const float*)d_in[2];
    const float* wk = (const float*)d_in[3];
    const float* bk = (const float*)d_in[4];
    const float* wv = (const float*)d_in[5];
    const float* bv = (const float*)d_in[6];
    float* out = (float*)d_out;

    const size_t nQ = (size_t)B_ * N_ * 8;        // 256K elems
    const size_t nX = (size_t)B_ * C_ * N_;       // 2M elems
    const size_t needed = (2 * nQ + nX) * sizeof(unsigned short);   // 5 MB

    if (ws_size >= needed) {
        unsigned short* Qh = (unsigned short*)d_ws;
        unsigned short* Kh = Qh + nQ;
        unsigned short* Xb = Kh + nQ;
        prep_kernel<<<B_ * (N_ / 64), 256, 0, stream>>>(x, wq, bq, wk, bk, Qh, Kh, Xb);
        attn_mfma11_kernel<<<B_ * (N_ / 64), 512, 0, stream>>>(Qh, Kh, Xb, wv, bv, out);
    } else {
        attn_fused_fallback<<<B_ * (N_ / 64), 256, 0, stream>>>(x, wq, bq, wk, bk, wv, bv, out);
    }
}

// Round 10
// 118.742 us; speedup vs baseline: 1.7293x; 1.7293x over previous
//
#include <hip/hip_runtime.h>
#include <hip/hip_bf16.h>

// SAGAN self-attention v14. B=8, C=64, N=4096, CQ=8.
// Algebraic refactor: out = Wv.(X.P^T)/d + bv  -- V never materialized.
//
// v13 post-mortem: substep restructure doubled live ranges -> spill at
// the zero-slack arch-64 cap (WRITE 244MB). Rule: NO attn-loop change
// that extends a live range. Reverted to v12 (52.0us attn, best).
//
// v14 = v12 with ONE zero-register change: the loop's __syncthreads
// (which emits s_waitcnt vmcnt(0) expcnt(0) lgkmcnt(0) + s_barrier,
// force-draining the mid-step K/X prefetch loads EVERY step) is replaced
// by s_waitcnt lgkmcnt(0) + raw s_barrier. The pair handshake only needs
// LDS ordering; prefetch loads now stay in flight across the barrier and
// their latency hides under the next step's p1/exp2 (T4 counted-wait).
// Safety: each wave's lgkmcnt(0) drains its own ds_writes (visibility)
// AND its step s-1 ds_reads (dbuf overwrite hazard); compiler inserts
// vmcnt waits before kf/xf consumers automatically.
// Lessons kept: launch_bounds(512,4) + arch<=64 (AGPR rounds 32->64),
//   no setprio/ones-MFMA/XCD-swizzle (v7), masked kf loads (v4),
//   prep v12 (float4 staging, packed uint2 stores).

#define B_   8
#define C_   64
#define N_   4096
#define LOG2E 1.44269504088896340736f

typedef short bf16x8 __attribute__((ext_vector_type(8)));
typedef float f32x4  __attribute__((ext_vector_type(4)));
typedef unsigned int uint32;

#if __has_builtin(__builtin_amdgcn_exp2f)
#define EXP2(x) __builtin_amdgcn_exp2f(x)
#else
#define EXP2(x) __expf((x) * 0.69314718055994530942f)
#endif

__device__ __forceinline__ unsigned short f2bf_rn(float f) {
    union { __hip_bfloat16 h; unsigned short u; } cv;
    cv.h = __float2bfloat16(f);
    return cv.u;
}
__device__ __forceinline__ uint32 pk_rn(float lo, float hi) {
    return (uint32)f2bf_rn(lo) | ((uint32)f2bf_rn(hi) << 16);
}
// RTZ pack (1 v_perm): bias cancels in softmax ratio. Verified R2/R3.
__device__ __forceinline__ uint32 pack_rtz(float lo, float hi) {
    return __builtin_amdgcn_perm(__float_as_uint(hi), __float_as_uint(lo), 0x07060302);
}

// ---------------------------------------------------------------------------
// prep v12 (kept): Xb = bf16(x), Qh/Kh = projections (Q pre-scaled).
// Grid: B * N/64 = 512 blocks, 256 threads.
// ---------------------------------------------------------------------------
__global__ __launch_bounds__(256) void prep_kernel(
    const float* __restrict__ x,
    const float* __restrict__ wq, const float* __restrict__ bq,
    const float* __restrict__ wk, const float* __restrict__ bk,
    unsigned short* __restrict__ Qh, unsigned short* __restrict__ Kh,
    unsigned short* __restrict__ Xb)
{
    __shared__ float Xs[C_][64];
    __shared__ float Wqk[16][C_];
    __shared__ float Bqk[16];

    const int t  = threadIdx.x;
    const int b  = blockIdx.x >> 6;
    const int p0 = (blockIdx.x & 63) << 6;

    #pragma unroll
    for (int k = 0; k < 4; ++k) {
        int i = t + k * 256;
        int o = i >> 6;
        Wqk[o][i & 63] = (o < 8) ? wq[i] * LOG2E : wk[i - 512];
    }
    if (t < 16) Bqk[t] = (t < 8) ? bq[t] * LOG2E : bk[t - 8];

    #pragma unroll
    for (int k = 0; k < 4; ++k) {
        int i = t + k * 256;                 // 1024 float4 total
        int c = i >> 4, p4 = (i & 15) << 2;
        const float4 v = *(const float4*)(x + ((size_t)b * C_ + c) * N_ + p0 + p4);
        *(float4*)&Xs[c][p4] = v;
        uint2 u;
        u.x = pk_rn(v.x, v.y);
        u.y = pk_rn(v.z, v.w);
        *(uint2*)(Xb + ((size_t)b * C_ + c) * N_ + p0 + p4) = u;
    }
    __syncthreads();

    const int pix = t & 63, grp = t >> 6;    // grp wave-uniform
    float a[4];
    #pragma unroll
    for (int r = 0; r < 4; ++r) a[r] = Bqk[grp * 4 + r];
    #pragma unroll
    for (int c = 0; c < C_; ++c) {
        float xv = Xs[c][pix];               // lanes consecutive: conflict-free
        #pragma unroll
        for (int r = 0; r < 4; ++r) a[r] += Wqk[grp * 4 + r][c] * xv;  // broadcast
    }
    uint2 u;
    u.x = pk_rn(a[0], a[1]);
    u.y = pk_rn(a[2], a[3]);
    unsigned short* dst = (grp & 2) ? Kh : Qh;
    *(uint2*)(dst + ((size_t)b * N_ + p0 + pix) * 8 + (grp & 1) * 4) = u;
}

// ---------------------------------------------------------------------------
// attn v14: grid B * N/64 = 512 blocks, 512 threads (8 waves = 4 pairs).
// Pair p: j in [p*1024,+1024), 32 steps x 32 j. Wave h of pair: jt=h in
// phase 1, channel half h in phase 2. Loop barrier = lgkmcnt(0)+s_barrier
// (prefetch loads stay in flight). Otherwise v10/v12 verbatim.
// ---------------------------------------------------------------------------
__global__ __launch_bounds__(512, 4) void attn_mfma12_kernel(
    const unsigned short* __restrict__ Qh,
    const unsigned short* __restrict__ Kh,
    const unsigned short* __restrict__ Xb,
    const float* __restrict__ wv, const float* __restrict__ bv,
    float* __restrict__ out)
{
    // LDS map (67584 B; 2 blocks/CU):
    //  loop:   [0,32K)   P: pair p at p*8192, dbuf +cur*4096; inside:
    //                    qt*1024 + l16*64 + XOR-swz offs (conflict-optimal)
    //  epilog: [0,48K)   6 dump slots x 8KB; then [0,16K) Wvs after reads
    //          [48K,64K) Or fp32 [64][64]
    //          [64K,+2K) Dn [8][64] fp32
    __shared__ __align__(16) char smem[67584];

    const int t    = threadIdx.x;
    const int w    = t >> 6;
    const int lane = t & 63;
    const int l16  = lane & 15;
    const int qd   = lane >> 4;
    const int p    = w & 3;     // pair -> j-slice
    const int h    = w >> 2;    // 0: jt0 + c[0,32) ; 1: jt1 + c[32,64)
    const int b    = blockIdx.x >> 6;
    const int i0   = (blockIdx.x & 63) << 6;

    const bf16x8 z8 = {};
    const f32x4  zf = {};

    // Q frags (phase-1 B-operand, B[k=ch][n=q], quads 1-3 zero: K-pad)
    bf16x8 qf[4];
    #pragma unroll
    for (int qt = 0; qt < 4; ++qt) {
        qf[qt] = z8;
        if (qd == 0)
            qf[qt] = *(const bf16x8*)(Qh + ((size_t)b * N_ + i0 + qt * 16 + l16) * 8);
    }

    // K rows for this wave's jt-half only; X rows for its channel half.
    const unsigned short* Kp = Kh + ((size_t)b * N_ + p * 1024 + h * 16) * 8;
    const unsigned short* Xp = Xb + ((size_t)b * C_ + h * 32) * N_ + p * 1024;

    f32x4 acc[2][4];   // [ct][qt]: O'(c=h*32+ct*16+qd*4+r, q=qt*16+l16)
    #pragma unroll
    for (int ct = 0; ct < 2; ++ct)
        #pragma unroll
        for (int qt = 0; qt < 4; ++qt) acc[ct][qt] = zf;
    float dsum[4] = {0.f, 0.f, 0.f, 0.f};

    // P addressing (v4-proven XOR swizzle); this wave writes its jt=h rows.
    const int swz   = (l16 & 3) << 2;
    const int pbase = p * 8192 + l16 * 64;
    const int woff  = ((h * 8 + qd * 2) ^ swz) << 2;
    const int roff  = ((qd * 4) ^ swz) << 2;

    // preload step 0
    bf16x8 kf[2], xf[2][2];
    kf[0] = z8;
    if (qd == 0) kf[0] = *(const bf16x8*)(Kp + (size_t)l16 * 8);
    #pragma unroll
    for (int ct = 0; ct < 2; ++ct)
        xf[0][ct] = *(const bf16x8*)(Xp + (size_t)(ct * 16 + l16) * N_ + qd * 8);

    #pragma unroll 2
    for (int s = 0; s < 32; ++s) {
        const int cur = s & 1, nxt = cur ^ 1;
        const int jb = s * 32;
        char* pb_ = smem + pbase + cur * 4096;

        // phase 1: S^T[j][q] for jt=h (rows j=jb+h*16+qd*4+r, col q=l16)
        f32x4 sf[4];
        #pragma unroll
        for (int qt = 0; qt < 4; ++qt)
            sf[qt] = __builtin_amdgcn_mfma_f32_16x16x32_bf16(kf[cur], qf[qt], zf, 0, 0, 0);

        // prefetch next step's K and X frags (vmcnt NOT drained at the
        // barrier below -- latency hides under next step's p1/exp2)
        if (s < 31) {
            bf16x8 nk = z8;
            if (qd == 0) nk = *(const bf16x8*)(Kp + (size_t)(jb + 32 + l16) * 8);
            kf[nxt] = nk;
            #pragma unroll
            for (int ct = 0; ct < 2; ++ct)
                xf[nxt][ct] = *(const bf16x8*)(Xp + (size_t)(ct * 16 + l16) * N_ + jb + 32 + qd * 8);
        }

        // exp2 -> denom + pack this wave's jt-half into the pair P buffer
        #pragma unroll
        for (int qt = 0; qt < 4; ++qt) {
            float e0 = EXP2(sf[qt][0]);
            float e1 = EXP2(sf[qt][1]);
            float e2 = EXP2(sf[qt][2]);
            float e3 = EXP2(sf[qt][3]);
            dsum[qt] += (e0 + e1) + (e2 + e3);
            uint2 u;
            u.x = pack_rtz(e0, e1);
            u.y = pack_rtz(e2, e3);
            *(uint2*)(pb_ + qt * 1024 + woff) = u;
        }

        // pair handshake WITHOUT vmcnt drain: lgkmcnt(0) proves this
        // wave's ds_writes (P visibility) AND its step s-1 ds_reads
        // (dbuf overwrite hazard) are complete; s_barrier makes it
        // block-wide. Prefetch global loads stay in flight.
        asm volatile("s_waitcnt lgkmcnt(0)" ::: "memory");
        __builtin_amdgcn_s_barrier();

        // phase 2: O'(half h) += X . P^T, full 32-j slice from pair buffer
        #pragma unroll
        for (int qt = 0; qt < 4; ++qt) {
            bf16x8 pbf = *(const bf16x8*)(pb_ + qt * 1024 + roff);
            #pragma unroll
            for (int ct = 0; ct < 2; ++ct)
                acc[ct][qt] = __builtin_amdgcn_mfma_f32_16x16x32_bf16(xf[cur][ct], pbf, acc[ct][qt], 0, 0, 0);
        }
    }

    // ---- denominator partials -> Dn[w][64] at [64K,+2K) ----
    #pragma unroll
    for (int qt = 0; qt < 4; ++qt) {
        float v = dsum[qt];
        v += __shfl_xor(v, 16, 64);
        v += __shfl_xor(v, 32, 64);
        if (qd == 0) *(float*)(smem + 65536 + (w * 64 + qt * 16 + l16) * 4) = v;
    }

    // ---- cross-wave O' reduce: halves reduce independently ----
    __syncthreads();                                   // S1: loop LDS done
    if (p != 0) {                                      // 6 dumpers, 8KB each
        const int slot = h * 3 + (p - 1);
        char* rb = smem + slot * 8192;
        #pragma unroll
        for (int ct = 0; ct < 2; ++ct)
            #pragma unroll
            for (int qt = 0; qt < 4; ++qt)
                *(f32x4*)(rb + (ct * 4 + qt) * 1024 + lane * 16) = acc[ct][qt];
    }
    __syncthreads();                                   // S2
    if (p == 0) {                                      // w0 (ct01), w4 (ct23)
        #pragma unroll
        for (int rr = 0; rr < 3; ++rr) {
            const char* rb = smem + (h * 3 + rr) * 8192;
            #pragma unroll
            for (int ct = 0; ct < 2; ++ct)
                #pragma unroll
                for (int qt = 0; qt < 4; ++qt)
                    acc[ct][qt] += *(const f32x4*)(rb + (ct * 4 + qt) * 1024 + lane * 16);
        }
        float* Or = (float*)(smem + 49152);
        #pragma unroll
        for (int ct = 0; ct < 2; ++ct)
            #pragma unroll
            for (int qt = 0; qt < 4; ++qt)
                #pragma unroll
                for (int r = 0; r < 4; ++r)
                    Or[(h * 32 + ct * 16 + qd * 4 + r) * 64 + qt * 16 + l16] = acc[ct][qt][r];
    }
    __syncthreads();                                   // S3: dump reads done
    {   // stage Wv fp32 -> [0,16K)
        float* Wvs = (float*)smem;
        for (int i = t; i < 4096; i += 512) Wvs[i] = wv[i];
    }
    __syncthreads();                                   // S4

    // ---- epilogue: out = Wv.O'/d + bv, fp32, all 8 waves ----
    const int q = t & 63, grp = t >> 6;                // grp = wave = c-group
    const float* Wvs = (const float*)smem;
    const float* Or  = (const float*)(smem + 49152);
    const float* Dn  = (const float*)(smem + 65536);
    float dtot = 0.f;
    #pragma unroll
    for (int r = 0; r < 8; ++r) dtot += Dn[r * 64 + q];
    const float inv = 1.0f / dtot;
    float o[8];
    #pragma unroll
    for (int r = 0; r < 8; ++r) o[r] = 0.f;
    for (int k = 0; k < 64; ++k) {
        float ov = Or[k * 64 + q];                      // lanes consecutive q
        #pragma unroll
        for (int r = 0; r < 8; ++r)
            o[r] += Wvs[(grp * 8 + r) * 64 + k] * ov;   // broadcast
    }
    #pragma unroll
    for (int r = 0; r < 8; ++r)
        out[((size_t)b * C_ + grp * 8 + r) * N_ + i0 + q] = o[r] * inv + bv[grp * 8 + r];
}

// ---------------------------------------------------------------------------
// Fallback (workspace too small): round-1 fused fp32 flash kernel (verified).
// ---------------------------------------------------------------------------
__global__ __launch_bounds__(256) void attn_fused_fallback(
    const float* __restrict__ x,
    const float* __restrict__ wq, const float* __restrict__ bq,
    const float* __restrict__ wk, const float* __restrict__ bk,
    const float* __restrict__ wv, const float* __restrict__ bv,
    float* __restrict__ out)
{
    __shared__ float Qs[64][8];
    __shared__ float Ks[8][64];
    __shared__ float Vs[64][C_];
    __shared__ float Ws[64][64 + 1];
    __shared__ float Xs[C_ * 64];
    __shared__ float Wks[8][C_];
    __shared__ float Wvs[C_][C_ + 1];

    const int t     = threadIdx.x;
    const int b     = blockIdx.x / (N_ / 64);
    const int i0    = (blockIdx.x % (N_ / 64)) * 64;
    const int jlane = t & 63;
    const int wgrp  = t >> 6;

    for (int l = t; l < 8 * C_;  l += 256) Wks[l >> 6][l & 63] = wk[l];
    for (int l = t; l < C_ * C_; l += 256) Wvs[l >> 6][l & 63] = wv[l];
    for (int l = t; l < C_ * 64; l += 256)
        Xs[(l >> 6) * 64 + (l & 63)] = x[((size_t)b * C_ + (l >> 6)) * N_ + i0 + (l & 63)];
    __syncthreads();
    {
        int qi = jlane;
        #pragma unroll
        for (int r = 0; r < 2; ++r) {
            int cc = wgrp * 2 + r;
            float a = bq[cc];
            for (int c = 0; c < C_; ++c) a += wq[cc * C_ + c] * Xs[c * 64 + qi];
            Qs[qi][cc] = a;
        }
    }
    __syncthreads();

    const int qi2 = t >> 2;
    const int cb  = (t & 3) << 4;
    float accv[16];
    #pragma unroll
    for (int r = 0; r < 16; ++r) accv[r] = 0.f;
    float denom = 0.f;

    for (int j0 = 0; j0 < N_; j0 += 64) {
        for (int l = t; l < C_ * 64; l += 256)
            Xs[(l >> 6) * 64 + (l & 63)] = x[((size_t)b * C_ + (l >> 6)) * N_ + j0 + (l & 63)];
        __syncthreads();
        {
            int j = jlane;
            #pragma unroll
            for (int r = 0; r < 2; ++r) {
                int cc = wgrp * 2 + r;
                float a = bk[cc];
                for (int c = 0; c < C_; ++c) a += Wks[cc][c] * Xs[c * 64 + j];
                Ks[cc][j] = a;
            }
        }
        {
            int vc = jlane;
            #pragma unroll 2
            for (int r = 0; r < 16; ++r) {
                int j = wgrp * 16 + r;
                float a = bv[vc];
                for (int c = 0; c < C_; ++c) a += Wvs[vc][c] * Xs[c * 64 + j];
                Vs[j][vc] = a;
            }
        }
        __syncthreads();
        {
            float kreg[8];
            #pragma unroll
            for (int cc = 0; cc < 8; ++cc) kreg[cc] = Ks[cc][jlane];
            #pragma unroll 4
            for (int r = 0; r < 16; ++r) {
                int qi = wgrp * 16 + r;
                float e = 0.f;
                #pragma unroll
                for (int cc = 0; cc < 8; ++cc) e += Qs[qi][cc] * kreg[cc];
                Ws[qi][jlane] = __expf(e);
            }
        }
        __syncthreads();
        #pragma unroll 4
        for (int j = 0; j < 64; ++j) {
            float wv2 = Ws[qi2][j];
            denom += wv2;
            const float4* vrow = (const float4*)(&Vs[j][cb]);
            float4 v0 = vrow[0], v1 = vrow[1], v2 = vrow[2], v3 = vrow[3];
            accv[0]  += wv2 * v0.x; accv[1]  += wv2 * v0.y; accv[2]  += wv2 * v0.z; accv[3]  += wv2 * v0.w;
            accv[4]  += wv2 * v1.x; accv[5]  += wv2 * v1.y; accv[6]  += wv2 * v1.z; accv[7]  += wv2 * v1.w;
            accv[8]  += wv2 * v2.x; accv[9]  += wv2 * v2.y; accv[10] += wv2 * v2.z; accv[11] += wv2 * v2.w;
            accv[12] += wv2 * v3.x; accv[13] += wv2 * v3.y; accv[14] += wv2 * v3.z; accv[15] += wv2 * v3.w;
        }
        __syncthreads();
    }

    const float inv = 1.0f / denom;
    #pragma unroll
    for (int r = 0; r < 16; ++r)
        out[((size_t)b * C_ + cb + r) * N_ + i0 + qi2] = accv[r] * inv;
}

// ---------------------------------------------------------------------------
extern "C" void kernel_launch(void* const* d_in, const int* in_sizes, int n_in,
                              void* d_out, int out_size, void* d_ws, size_t ws_size,
                              hipStream_t stream)
{
    const float* x  = (const float*)d_in[0];
    const float* wq = (const float*)d_in[1];
    const float* bq = (const float*)d_in[2];
    const float* wk = (const float*)d_in[3];
    const float* bk = (const float*)d_in[4];
    const float* wv = (const float*)d_in[5];
    const float* bv = (const float*)d_in[6];
    float* out = (float*)d_out;

    const size_t nQ = (size_t)B_ * N_ * 8;        // 256K elems
    const size_t nX = (size_t)B_ * C_ * N_;       // 2M elems
    const size_t needed = (2 * nQ + nX) * sizeof(unsigned short);   // 5 MB

    if (ws_size >= needed) {
        unsigned short* Qh = (unsigned short*)d_ws;
        unsigned short* Kh = Qh + nQ;
        unsigned short* Xb = Kh + nQ;
        prep_kernel<<<B_ * (N_ / 64), 256, 0, stream>>>(x, wq, bq, wk, bk, Qh, Kh, Xb);
        attn_mfma12_kernel<<<B_ * (N_ / 64), 512, 0, stream>>>(Qh, Kh, Xb, wv, bv, out);
    } else {
        attn_fused_fallback<<<B_ * (N_ / 64), 256, 0, stream>>>(x, wq, bq, wk, bk, wv, bv, out);
    }
}